// Round 1
// baseline (8205.582 us; speedup 1.0000x reference)
//
#include <hip/hip_runtime.h>
#include <cstddef>

#define NN 50000
#define HH 128
#define TT 4
#define EE 150000

__device__ __forceinline__ float sigm(float v) { return 1.0f / (1.0f + __expf(-v)); }

__device__ __forceinline__ float gru_elem(float xr, float xz, float xn,
                                          float hr, float hz, float hn, float h) {
    float r = sigm(xr + hr);
    float z = sigm(xz + hz);
    float nn = tanhf(xn + r * hn);
    return (1.f - z) * nn + z * h;
}

// ---------------- degree counts (once per call) ----------------
__global__ __launch_bounds__(256)
void deg_kernel(const int* __restrict__ edges, int* __restrict__ deg) {
    int eg = blockIdx.x * 256 + threadIdx.x;
    if (eg >= TT * EE) return;
    int t = eg / EE;
    int tgt = edges[eg * 2 + 1];
    atomicAdd(&deg[t * NN + tgt], 1);
}

// ---------------- neighbor-sum scatter: S[t][tgt] += h[src] ----------------
// grid = T*E*32/256 exactly; 32 lanes (float4 each) per edge
__global__ __launch_bounds__(256)
void scatter_kernel(const int* __restrict__ edges, const float* __restrict__ h,
                    float* __restrict__ S) {
    int gid = blockIdx.x * 256 + threadIdx.x;
    int eg = gid >> 5;
    int c = (gid & 31) * 4;
    int t = eg / EE;
    int src = edges[eg * 2];
    int tgt = edges[eg * 2 + 1];
    const float4 v = *(const float4*)&h[(size_t)src * HH + c];
    float* dst = &S[((size_t)t * NN + tgt) * HH + c];
    atomicAdd(dst + 0, v.x);
    atomicAdd(dst + 1, v.y);
    atomicAdd(dst + 2, v.z);
    atomicAdd(dst + 3, v.w);
}

// ---------------- inc = sum_t S[t] @ W[t]^T + (deg-weighted bias) ----------------
// K = T*H = 512 segmented over t. Tile 128x128, 256 threads, 8x8 micro-tile.
__global__ __launch_bounds__(256)
void inc_gemm(const float* __restrict__ S, const float* __restrict__ W,
              const float* __restrict__ bmsg, const int* __restrict__ deg,
              float* __restrict__ inc) {
    __shared__ float As[8][132];
    __shared__ float Bs[8][132];
    __shared__ float bsh[4][128];
    const int tid = threadIdx.x;
    const int mbase = blockIdx.x * 128;
    ((float*)bsh)[tid] = bmsg[tid];
    ((float*)bsh)[tid + 256] = bmsg[tid + 256];
    const int row = tid >> 1;
    const int half = tid & 1;
    const int tf = tid & 15;
    const int tm = tid >> 4;
    float acc[8][8] = {};
    for (int kc = 0; kc < 64; ++kc) {
        const int gk = kc * 8 + half * 4;
        const int t = gk >> 7;
        const int h = gk & 127;
        const int grow = mbase + row;
        float4 av = make_float4(0.f, 0.f, 0.f, 0.f);
        if (grow < NN) av = *(const float4*)&S[((size_t)t * NN + grow) * HH + h];
        const float4 bv = *(const float4*)&W[((size_t)t * HH + row) * HH + h];
        __syncthreads();
        const int k4 = half * 4;
        As[k4 + 0][row] = av.x; As[k4 + 1][row] = av.y;
        As[k4 + 2][row] = av.z; As[k4 + 3][row] = av.w;
        Bs[k4 + 0][row] = bv.x; Bs[k4 + 1][row] = bv.y;
        Bs[k4 + 2][row] = bv.z; Bs[k4 + 3][row] = bv.w;
        __syncthreads();
        #pragma unroll
        for (int k = 0; k < 8; ++k) {
            float4 a0 = *(const float4*)&As[k][tm * 4];
            float4 a1 = *(const float4*)&As[k][tm * 4 + 64];
            float4 b0 = *(const float4*)&Bs[k][tf * 4];
            float4 b1 = *(const float4*)&Bs[k][tf * 4 + 64];
            float a[8] = {a0.x, a0.y, a0.z, a0.w, a1.x, a1.y, a1.z, a1.w};
            float b[8] = {b0.x, b0.y, b0.z, b0.w, b1.x, b1.y, b1.z, b1.w};
            #pragma unroll
            for (int i = 0; i < 8; ++i)
                #pragma unroll
                for (int j = 0; j < 8; ++j)
                    acc[i][j] = fmaf(a[i], b[j], acc[i][j]);
        }
    }
    // bias table per (t, fcol)
    float bs[4][8];
    #pragma unroll
    for (int t = 0; t < 4; ++t)
        #pragma unroll
        for (int j = 0; j < 8; ++j) {
            const int fc = (j < 4) ? (tf * 4 + j) : (64 + tf * 4 + (j - 4));
            bs[t][j] = bsh[t][fc];
        }
    #pragma unroll
    for (int mi = 0; mi < 8; ++mi) {
        const int lm = (mi < 4) ? (tm * 4 + mi) : (64 + tm * 4 + (mi - 4));
        const int gm = mbase + lm;
        if (gm < NN) {
            const float d0 = (float)deg[gm];
            const float d1 = (float)deg[NN + gm];
            const float d2 = (float)deg[2 * NN + gm];
            const float d3 = (float)deg[3 * NN + gm];
            float v[8];
            #pragma unroll
            for (int j = 0; j < 8; ++j)
                v[j] = acc[mi][j] + d0 * bs[0][j] + d1 * bs[1][j] + d2 * bs[2][j] + d3 * bs[3][j];
            *(float4*)&inc[(size_t)gm * HH + tf * 4] = make_float4(v[0], v[1], v[2], v[3]);
            *(float4*)&inc[(size_t)gm * HH + tf * 4 + 64] = make_float4(v[4], v[5], v[6], v[7]);
        }
    }
}

// ---------------- generic C = [A0|A1] @ B^T + bias ----------------
// A0 rows lda=K0 (k < K0); A1 rows lda=K-K0 (k >= K0). B is (Ftot, ldb) row-major.
__global__ __launch_bounds__(256)
void gemm_bias(const float* __restrict__ A0, const float* __restrict__ A1,
               int K0, int K,
               const float* __restrict__ B, int ldb,
               const float* __restrict__ bias,
               float* __restrict__ C, int ldc, int M) {
    __shared__ float As[8][132];
    __shared__ float Bs[8][132];
    const int tid = threadIdx.x;
    const int mbase = blockIdx.x * 128;
    const int fbase = blockIdx.y * 128;
    const int row = tid >> 1;
    const int half = tid & 1;
    const int tf = tid & 15;
    const int tm = tid >> 4;
    float acc[8][8] = {};
    const int nk = K >> 3;
    for (int kc = 0; kc < nk; ++kc) {
        const int gk = kc * 8 + half * 4;
        const int grow = mbase + row;
        float4 av = make_float4(0.f, 0.f, 0.f, 0.f);
        if (grow < M) {
            if (gk < K0) av = *(const float4*)&A0[(size_t)grow * K0 + gk];
            else         av = *(const float4*)&A1[(size_t)grow * (K - K0) + (gk - K0)];
        }
        const int frow = fbase + row;
        const float4 bv = *(const float4*)&B[(size_t)frow * ldb + gk];
        __syncthreads();
        const int k4 = half * 4;
        As[k4 + 0][row] = av.x; As[k4 + 1][row] = av.y;
        As[k4 + 2][row] = av.z; As[k4 + 3][row] = av.w;
        Bs[k4 + 0][row] = bv.x; Bs[k4 + 1][row] = bv.y;
        Bs[k4 + 2][row] = bv.z; Bs[k4 + 3][row] = bv.w;
        __syncthreads();
        #pragma unroll
        for (int k = 0; k < 8; ++k) {
            float4 a0 = *(const float4*)&As[k][tm * 4];
            float4 a1 = *(const float4*)&As[k][tm * 4 + 64];
            float4 b0 = *(const float4*)&Bs[k][tf * 4];
            float4 b1 = *(const float4*)&Bs[k][tf * 4 + 64];
            float a[8] = {a0.x, a0.y, a0.z, a0.w, a1.x, a1.y, a1.z, a1.w};
            float b[8] = {b0.x, b0.y, b0.z, b0.w, b1.x, b1.y, b1.z, b1.w};
            #pragma unroll
            for (int i = 0; i < 8; ++i)
                #pragma unroll
                for (int j = 0; j < 8; ++j)
                    acc[i][j] = fmaf(a[i], b[j], acc[i][j]);
        }
    }
    const float4 bb0 = *(const float4*)&bias[fbase + tf * 4];
    const float4 bb1 = *(const float4*)&bias[fbase + tf * 4 + 64];
    #pragma unroll
    for (int mi = 0; mi < 8; ++mi) {
        const int lm = (mi < 4) ? (tm * 4 + mi) : (64 + tm * 4 + (mi - 4));
        const int gm = mbase + lm;
        if (gm < M) {
            float4 v0 = make_float4(acc[mi][0] + bb0.x, acc[mi][1] + bb0.y,
                                    acc[mi][2] + bb0.z, acc[mi][3] + bb0.w);
            float4 v1 = make_float4(acc[mi][4] + bb1.x, acc[mi][5] + bb1.y,
                                    acc[mi][6] + bb1.z, acc[mi][7] + bb1.w);
            *(float4*)&C[(size_t)gm * ldc + fbase + tf * 4] = v0;
            *(float4*)&C[(size_t)gm * ldc + fbase + tf * 4 + 64] = v1;
        }
    }
}

// ---------------- GRU gates (elementwise) ----------------
// grid = N*32/256 exactly
__global__ __launch_bounds__(256)
void gate_kernel(const float* __restrict__ gx, const float* __restrict__ gh,
                 const float* __restrict__ hcur, float* __restrict__ hnext) {
    int gid = blockIdx.x * 256 + threadIdx.x;
    int n = gid >> 5;
    int c = (gid & 31) * 4;
    const size_t bx = (size_t)n * 384 + c;
    const float4 xr = *(const float4*)&gx[bx];
    const float4 xz = *(const float4*)&gx[bx + 128];
    const float4 xn = *(const float4*)&gx[bx + 256];
    const float4 hr = *(const float4*)&gh[bx];
    const float4 hz = *(const float4*)&gh[bx + 128];
    const float4 hn = *(const float4*)&gh[bx + 256];
    const float4 hv = *(const float4*)&hcur[(size_t)n * HH + c];
    float4 o;
    o.x = gru_elem(xr.x, xz.x, xn.x, hr.x, hz.x, hn.x, hv.x);
    o.y = gru_elem(xr.y, xz.y, xn.y, hr.y, hz.y, hn.y, hv.y);
    o.z = gru_elem(xr.z, xz.z, xn.z, hr.z, hz.z, hn.z, hv.z);
    o.w = gru_elem(xr.w, xz.w, xn.w, hr.w, hz.w, hn.w, hv.w);
    *(float4*)&hnext[(size_t)n * HH + c] = o;
}

extern "C" void kernel_launch(void* const* d_in, const int* in_sizes, int n_in,
                              void* d_out, int out_size, void* d_ws, size_t ws_size,
                              hipStream_t stream) {
    (void)in_sizes; (void)n_in; (void)out_size; (void)ws_size;
    const float* x     = (const float*)d_in[0];
    const int*   edges = (const int*)d_in[1];
    const float* msg_W = (const float*)d_in[2];
    const float* msg_b = (const float*)d_in[3];
    const float* W0ih  = (const float*)d_in[4];
    const float* W0hh  = (const float*)d_in[5];
    const float* b0ih  = (const float*)d_in[6];
    const float* b0hh  = (const float*)d_in[7];
    const float* W1ih  = (const float*)d_in[8];
    const float* W1hh  = (const float*)d_in[9];
    const float* b1ih  = (const float*)d_in[10];
    const float* b1hh  = (const float*)d_in[11];
    float* out = (float*)d_out;

    // workspace layout (floats). S (25.6M) aliases gx+gh region (38.4M): disjoint lifetimes.
    float* ws   = (float*)d_ws;
    float* Sbuf = ws;                    // T*N*H = 25,600,000 floats
    float* gx   = ws;                    // N*384 = 19,200,000
    float* gh   = ws + 19200000;         // N*384
    float* inc  = ws + 38400000;         // N*H  =  6,400,000
    float* hA   = ws + 44800000;         // N*H
    int*   deg  = (int*)(ws + 51200000); // T*N ints

    hipMemcpyAsync(out, x, (size_t)NN * HH * sizeof(float), hipMemcpyDeviceToDevice, stream);
    hipMemsetAsync(deg, 0, (size_t)TT * NN * sizeof(int), stream);
    deg_kernel<<<(TT * EE + 255) / 256, 256, 0, stream>>>(edges, deg);

    const int mblocks = (NN + 127) / 128;  // 391
    for (int s = 0; s < 6; ++s) {
        const int l = s / 3;
        const float* hcur = (s % 2 == 0) ? out : hA;
        float*       hnext = (s % 2 == 0) ? hA : out;

        hipMemsetAsync(Sbuf, 0, (size_t)TT * NN * HH * sizeof(float), stream);
        scatter_kernel<<<(TT * EE * 32) / 256, 256, 0, stream>>>(edges, hcur, Sbuf);
        inc_gemm<<<mblocks, 256, 0, stream>>>(Sbuf, msg_W + (size_t)l * TT * HH * HH,
                                              msg_b + (size_t)l * TT * HH, deg, inc);
        if (l == 0) {
            gemm_bias<<<dim3(mblocks, 3), 256, 0, stream>>>(inc, inc, 128, 128, W0ih, 128,
                                                            b0ih, gx, 384, NN);
            gemm_bias<<<dim3(mblocks, 3), 256, 0, stream>>>(hcur, hcur, 128, 128, W0hh, 128,
                                                            b0hh, gh, 384, NN);
        } else {
            gemm_bias<<<dim3(mblocks, 3), 256, 0, stream>>>(x, inc, 128, 256, W1ih, 256,
                                                            b1ih, gx, 384, NN);
            gemm_bias<<<dim3(mblocks, 3), 256, 0, stream>>>(hcur, hcur, 128, 128, W1hh, 128,
                                                            b1hh, gh, 384, NN);
        }
        gate_kernel<<<(NN * 32) / 256, 256, 0, stream>>>(gx, gh, hcur, hnext);
    }
    // step 6 (s=5) writes d_out — final h lands in d_out.
}

// Round 2
// 2326.322 us; speedup vs baseline: 3.5273x; 3.5273x over previous
//
#include <hip/hip_runtime.h>
#include <cstddef>

#define NN 50000
#define HH 128
#define TT 4
#define EE 150000
#define TN (TT * NN)          // 200000 rows (t, n)
#define NBLK 782              // ceil(TN/256)

__device__ __forceinline__ float sigm(float v) { return 1.0f / (1.0f + __expf(-v)); }

__device__ __forceinline__ float gru_elem(float xr, float xz, float xn,
                                          float hr, float hz, float hn, float h) {
    float r = sigm(xr + hr);
    float z = sigm(xz + hz);
    float nn = tanhf(xn + r * hn);
    return (1.f - z) * nn + z * h;
}

// ================= CSR build (once per call) =================
__global__ __launch_bounds__(256)
void deg_kernel(const int* __restrict__ edges, int* __restrict__ deg) {
    int eg = blockIdx.x * 256 + threadIdx.x;
    if (eg >= TT * EE) return;
    int t = eg / EE;
    int tgt = edges[eg * 2 + 1];
    atomicAdd(&deg[t * NN + tgt], 1);
}

// per-block inclusive scan; emits local inclusive scans + block totals
__global__ __launch_bounds__(256)
void scan_block(const int* __restrict__ deg, int* __restrict__ locscan,
                int* __restrict__ blocksum) {
    __shared__ int sh[256];
    const int tid = threadIdx.x;
    const int i = blockIdx.x * 256 + tid;
    int v = (i < TN) ? deg[i] : 0;
    sh[tid] = v;
    __syncthreads();
    #pragma unroll
    for (int off = 1; off < 256; off <<= 1) {
        int t = (tid >= off) ? sh[tid - off] : 0;
        __syncthreads();
        sh[tid] += t;
        __syncthreads();
    }
    if (i < TN) locscan[i] = sh[tid];
    if (tid == 255) blocksum[blockIdx.x] = sh[255];
}

// single-block exclusive scan of the NBLK block totals
__global__ __launch_bounds__(1024)
void scan_partials(const int* __restrict__ blocksum, int* __restrict__ blockpref) {
    __shared__ int sh[1024];
    const int tid = threadIdx.x;
    sh[tid] = (tid < NBLK) ? blocksum[tid] : 0;
    __syncthreads();
    #pragma unroll
    for (int off = 1; off < 1024; off <<= 1) {
        int t = (tid >= off) ? sh[tid - off] : 0;
        __syncthreads();
        sh[tid] += t;
        __syncthreads();
    }
    if (tid < NBLK) blockpref[tid] = (tid == 0) ? 0 : sh[tid - 1];
}

__global__ __launch_bounds__(256)
void fill_base(const int* __restrict__ deg, const int* __restrict__ locscan,
               const int* __restrict__ blockpref, int* __restrict__ base,
               int* __restrict__ cursor) {
    const int i = blockIdx.x * 256 + threadIdx.x;
    if (i >= TN) return;
    const int incl = locscan[i] + blockpref[blockIdx.x];
    base[i] = incl - deg[i];
    cursor[i] = 0;
    if (i == TN - 1) base[TN] = incl;
}

__global__ __launch_bounds__(256)
void place_kernel(const int* __restrict__ edges, const int* __restrict__ base,
                  int* __restrict__ cursor, unsigned short* __restrict__ srcs) {
    int eg = blockIdx.x * 256 + threadIdx.x;
    if (eg >= TT * EE) return;
    int t = eg / EE;
    int src = edges[eg * 2];
    int tgt = edges[eg * 2 + 1];
    int idx = t * NN + tgt;
    int p = base[idx] + atomicAdd(&cursor[idx], 1);
    srcs[p] = (unsigned short)src;
}

// ================= neighbor-sum gather: S[row] = sum h[src] =================
// 32 lanes (float4 each) per (t,n) row; grid exact: TN*32/256
__global__ __launch_bounds__(256)
void gather_kernel(const int* __restrict__ base, const unsigned short* __restrict__ srcs,
                   const float* __restrict__ h, float* __restrict__ S) {
    int gid = blockIdx.x * 256 + threadIdx.x;
    int row = gid >> 5;
    int c = (gid & 31) * 4;
    const int p0 = base[row];
    const int p1 = base[row + 1];
    float4 acc = make_float4(0.f, 0.f, 0.f, 0.f);
    for (int p = p0; p < p1; ++p) {
        const int s = srcs[p];
        const float4 v = *(const float4*)&h[(size_t)s * HH + c];
        acc.x += v.x; acc.y += v.y; acc.z += v.z; acc.w += v.w;
    }
    *(float4*)&S[(size_t)row * HH + c] = acc;
}

// ========== inc = sum_t S[t] @ W[t]^T + deg-weighted bias ==========
__global__ __launch_bounds__(256)
void inc_gemm(const float* __restrict__ S, const float* __restrict__ W,
              const float* __restrict__ bmsg, const int* __restrict__ base,
              float* __restrict__ inc) {
    __shared__ float As[8][132];
    __shared__ float Bs[8][132];
    __shared__ float bsh[4][128];
    const int tid = threadIdx.x;
    const int mbase = blockIdx.x * 128;
    ((float*)bsh)[tid] = bmsg[tid];
    ((float*)bsh)[tid + 256] = bmsg[tid + 256];
    const int row = tid >> 1;
    const int half = tid & 1;
    const int tf = tid & 15;
    const int tm = tid >> 4;
    float acc[8][8] = {};
    for (int kc = 0; kc < 64; ++kc) {
        const int gk = kc * 8 + half * 4;
        const int t = gk >> 7;
        const int h = gk & 127;
        const int grow = mbase + row;
        float4 av = make_float4(0.f, 0.f, 0.f, 0.f);
        if (grow < NN) av = *(const float4*)&S[((size_t)t * NN + grow) * HH + h];
        const float4 bv = *(const float4*)&W[((size_t)t * HH + row) * HH + h];
        __syncthreads();
        const int k4 = half * 4;
        As[k4 + 0][row] = av.x; As[k4 + 1][row] = av.y;
        As[k4 + 2][row] = av.z; As[k4 + 3][row] = av.w;
        Bs[k4 + 0][row] = bv.x; Bs[k4 + 1][row] = bv.y;
        Bs[k4 + 2][row] = bv.z; Bs[k4 + 3][row] = bv.w;
        __syncthreads();
        #pragma unroll
        for (int k = 0; k < 8; ++k) {
            float4 a0 = *(const float4*)&As[k][tm * 4];
            float4 a1 = *(const float4*)&As[k][tm * 4 + 64];
            float4 b0 = *(const float4*)&Bs[k][tf * 4];
            float4 b1 = *(const float4*)&Bs[k][tf * 4 + 64];
            float a[8] = {a0.x, a0.y, a0.z, a0.w, a1.x, a1.y, a1.z, a1.w};
            float b[8] = {b0.x, b0.y, b0.z, b0.w, b1.x, b1.y, b1.z, b1.w};
            #pragma unroll
            for (int i = 0; i < 8; ++i)
                #pragma unroll
                for (int j = 0; j < 8; ++j)
                    acc[i][j] = fmaf(a[i], b[j], acc[i][j]);
        }
    }
    float bs[4][8];
    #pragma unroll
    for (int t = 0; t < 4; ++t)
        #pragma unroll
        for (int j = 0; j < 8; ++j) {
            const int fc = (j < 4) ? (tf * 4 + j) : (64 + tf * 4 + (j - 4));
            bs[t][j] = bsh[t][fc];
        }
    #pragma unroll
    for (int mi = 0; mi < 8; ++mi) {
        const int lm = (mi < 4) ? (tm * 4 + mi) : (64 + tm * 4 + (mi - 4));
        const int gm = mbase + lm;
        if (gm < NN) {
            const float d0 = (float)(base[gm + 1] - base[gm]);
            const float d1 = (float)(base[NN + gm + 1] - base[NN + gm]);
            const float d2 = (float)(base[2 * NN + gm + 1] - base[2 * NN + gm]);
            const float d3 = (float)(base[3 * NN + gm + 1] - base[3 * NN + gm]);
            float v[8];
            #pragma unroll
            for (int j = 0; j < 8; ++j)
                v[j] = acc[mi][j] + d0 * bs[0][j] + d1 * bs[1][j] + d2 * bs[2][j] + d3 * bs[3][j];
            *(float4*)&inc[(size_t)gm * HH + tf * 4] = make_float4(v[0], v[1], v[2], v[3]);
            *(float4*)&inc[(size_t)gm * HH + tf * 4 + 64] = make_float4(v[4], v[5], v[6], v[7]);
        }
    }
}

// ========== generic C = [A0|A1] @ B^T + bias ==========
__global__ __launch_bounds__(256)
void gemm_bias(const float* __restrict__ A0, const float* __restrict__ A1,
               int K0, int K,
               const float* __restrict__ B, int ldb,
               const float* __restrict__ bias,
               float* __restrict__ C, int ldc, int M) {
    __shared__ float As[8][132];
    __shared__ float Bs[8][132];
    const int tid = threadIdx.x;
    const int mbase = blockIdx.x * 128;
    const int fbase = blockIdx.y * 128;
    const int row = tid >> 1;
    const int half = tid & 1;
    const int tf = tid & 15;
    const int tm = tid >> 4;
    float acc[8][8] = {};
    const int nk = K >> 3;
    for (int kc = 0; kc < nk; ++kc) {
        const int gk = kc * 8 + half * 4;
        const int grow = mbase + row;
        float4 av = make_float4(0.f, 0.f, 0.f, 0.f);
        if (grow < M) {
            if (gk < K0) av = *(const float4*)&A0[(size_t)grow * K0 + gk];
            else         av = *(const float4*)&A1[(size_t)grow * (K - K0) + (gk - K0)];
        }
        const int frow = fbase + row;
        const float4 bv = *(const float4*)&B[(size_t)frow * ldb + gk];
        __syncthreads();
        const int k4 = half * 4;
        As[k4 + 0][row] = av.x; As[k4 + 1][row] = av.y;
        As[k4 + 2][row] = av.z; As[k4 + 3][row] = av.w;
        Bs[k4 + 0][row] = bv.x; Bs[k4 + 1][row] = bv.y;
        Bs[k4 + 2][row] = bv.z; Bs[k4 + 3][row] = bv.w;
        __syncthreads();
        #pragma unroll
        for (int k = 0; k < 8; ++k) {
            float4 a0 = *(const float4*)&As[k][tm * 4];
            float4 a1 = *(const float4*)&As[k][tm * 4 + 64];
            float4 b0 = *(const float4*)&Bs[k][tf * 4];
            float4 b1 = *(const float4*)&Bs[k][tf * 4 + 64];
            float a[8] = {a0.x, a0.y, a0.z, a0.w, a1.x, a1.y, a1.z, a1.w};
            float b[8] = {b0.x, b0.y, b0.z, b0.w, b1.x, b1.y, b1.z, b1.w};
            #pragma unroll
            for (int i = 0; i < 8; ++i)
                #pragma unroll
                for (int j = 0; j < 8; ++j)
                    acc[i][j] = fmaf(a[i], b[j], acc[i][j]);
        }
    }
    const float4 bb0 = *(const float4*)&bias[fbase + tf * 4];
    const float4 bb1 = *(const float4*)&bias[fbase + tf * 4 + 64];
    #pragma unroll
    for (int mi = 0; mi < 8; ++mi) {
        const int lm = (mi < 4) ? (tm * 4 + mi) : (64 + tm * 4 + (mi - 4));
        const int gm = mbase + lm;
        if (gm < M) {
            float4 v0 = make_float4(acc[mi][0] + bb0.x, acc[mi][1] + bb0.y,
                                    acc[mi][2] + bb0.z, acc[mi][3] + bb0.w);
            float4 v1 = make_float4(acc[mi][4] + bb1.x, acc[mi][5] + bb1.y,
                                    acc[mi][6] + bb1.z, acc[mi][7] + bb1.w);
            *(float4*)&C[(size_t)gm * ldc + fbase + tf * 4] = v0;
            *(float4*)&C[(size_t)gm * ldc + fbase + tf * 4 + 64] = v1;
        }
    }
}

// ========== GRU gates (elementwise) ==========
__global__ __launch_bounds__(256)
void gate_kernel(const float* __restrict__ gx, const float* __restrict__ gh,
                 const float* __restrict__ hcur, float* __restrict__ hnext) {
    int gid = blockIdx.x * 256 + threadIdx.x;
    int n = gid >> 5;
    int c = (gid & 31) * 4;
    const size_t bx = (size_t)n * 384 + c;
    const float4 xr = *(const float4*)&gx[bx];
    const float4 xz = *(const float4*)&gx[bx + 128];
    const float4 xn = *(const float4*)&gx[bx + 256];
    const float4 hr = *(const float4*)&gh[bx];
    const float4 hz = *(const float4*)&gh[bx + 128];
    const float4 hn = *(const float4*)&gh[bx + 256];
    const float4 hv = *(const float4*)&hcur[(size_t)n * HH + c];
    float4 o;
    o.x = gru_elem(xr.x, xz.x, xn.x, hr.x, hz.x, hn.x, hv.x);
    o.y = gru_elem(xr.y, xz.y, xn.y, hr.y, hz.y, hn.y, hv.y);
    o.z = gru_elem(xr.z, xz.z, xn.z, hr.z, hz.z, hn.z, hv.z);
    o.w = gru_elem(xr.w, xz.w, xn.w, hr.w, hz.w, hn.w, hv.w);
    *(float4*)&hnext[(size_t)n * HH + c] = o;
}

extern "C" void kernel_launch(void* const* d_in, const int* in_sizes, int n_in,
                              void* d_out, int out_size, void* d_ws, size_t ws_size,
                              hipStream_t stream) {
    (void)in_sizes; (void)n_in; (void)out_size; (void)ws_size;
    const float* x     = (const float*)d_in[0];
    const int*   edges = (const int*)d_in[1];
    const float* msg_W = (const float*)d_in[2];
    const float* msg_b = (const float*)d_in[3];
    const float* W0ih  = (const float*)d_in[4];
    const float* W0hh  = (const float*)d_in[5];
    const float* b0ih  = (const float*)d_in[6];
    const float* b0hh  = (const float*)d_in[7];
    const float* W1ih  = (const float*)d_in[8];
    const float* W1hh  = (const float*)d_in[9];
    const float* b1ih  = (const float*)d_in[10];
    const float* b1hh  = (const float*)d_in[11];
    float* out = (float*)d_out;

    // ---- workspace layout (floats) ----
    // Sbuf [0, 25.6M) aliases gx [0,19.2M) + gh head: disjoint lifetimes within a step.
    // Build temporaries alias ws start (dead before first gather).
    float* ws   = (float*)d_ws;
    float* Sbuf = ws;                    // T*N*H = 25,600,000 floats
    float* gx   = ws;                    // N*384 = 19,200,000
    float* gh   = ws + 19200000;         // N*384
    float* inc  = ws + 38400000;         // N*H  =  6,400,000
    float* hA   = ws + 44800000;         // N*H
    // persistent CSR beyond 51.2M floats: base (TN+1 ints) + srcs (T*E u16)
    int*            base = (int*)(ws + 51200000);       // 200,001 ints
    unsigned short* srcs = (unsigned short*)(base + 200004); // 600,000 u16 (1.2 MB)
    // build-time temporaries (alias S region)
    int* deg_tmp  = (int*)ws;            // TN
    int* locscan  = deg_tmp + TN;        // TN
    int* cursor   = deg_tmp + 2 * TN;    // TN
    int* blocksum = deg_tmp + 3 * TN;    // 1024
    int* blockpref= deg_tmp + 3 * TN + 1024;

    hipMemcpyAsync(out, x, (size_t)NN * HH * sizeof(float), hipMemcpyDeviceToDevice, stream);

    // ---- CSR build ----
    hipMemsetAsync(deg_tmp, 0, (size_t)TN * sizeof(int), stream);
    deg_kernel<<<(TT * EE + 255) / 256, 256, 0, stream>>>(edges, deg_tmp);
    scan_block<<<NBLK, 256, 0, stream>>>(deg_tmp, locscan, blocksum);
    scan_partials<<<1, 1024, 0, stream>>>(blocksum, blockpref);
    fill_base<<<NBLK, 256, 0, stream>>>(deg_tmp, locscan, blockpref, base, cursor);
    place_kernel<<<(TT * EE + 255) / 256, 256, 0, stream>>>(edges, base, cursor, srcs);

    const int mblocks = (NN + 127) / 128;  // 391
    for (int s = 0; s < 6; ++s) {
        const int l = s / 3;
        const float* hcur = (s % 2 == 0) ? out : hA;
        float*       hnext = (s % 2 == 0) ? hA : out;

        gather_kernel<<<(TN * 32) / 256, 256, 0, stream>>>(base, srcs, hcur, Sbuf);
        inc_gemm<<<mblocks, 256, 0, stream>>>(Sbuf, msg_W + (size_t)l * TT * HH * HH,
                                              msg_b + (size_t)l * TT * HH, base, inc);
        if (l == 0) {
            gemm_bias<<<dim3(mblocks, 3), 256, 0, stream>>>(inc, inc, 128, 128, W0ih, 128,
                                                            b0ih, gx, 384, NN);
            gemm_bias<<<dim3(mblocks, 3), 256, 0, stream>>>(hcur, hcur, 128, 128, W0hh, 128,
                                                            b0hh, gh, 384, NN);
        } else {
            gemm_bias<<<dim3(mblocks, 3), 256, 0, stream>>>(x, inc, 128, 256, W1ih, 256,
                                                            b1ih, gx, 384, NN);
            gemm_bias<<<dim3(mblocks, 3), 256, 0, stream>>>(hcur, hcur, 128, 128, W1hh, 128,
                                                            b1hh, gh, 384, NN);
        }
        gate_kernel<<<(NN * 32) / 256, 256, 0, stream>>>(gx, gh, hcur, hnext);
    }
}

// Round 3
// 992.220 us; speedup vs baseline: 8.2699x; 2.3446x over previous
//
#include <hip/hip_runtime.h>
#include <cstddef>

#define NN 50000
#define HH 128
#define TT 4
#define EE 150000
#define TN (TT * NN)          // 200000 rows (t, n)
#define NBLK 782              // ceil(TN/256)

typedef __attribute__((ext_vector_type(8))) short bfrag8;   // 8 bf16 = 4 VGPRs
typedef __attribute__((ext_vector_type(4))) float f32x4;

__device__ __forceinline__ float sigm(float v) { return 1.0f / (1.0f + __expf(-v)); }

__device__ __forceinline__ float gru_elem(float xr, float xz, float xn,
                                          float hr, float hz, float hn, float h) {
    float r = sigm(xr + hr);
    float z = sigm(xz + hz);
    float nn = tanhf(xn + r * hn);
    return (1.f - z) * nn + z * h;
}

__device__ __forceinline__ unsigned short f2b(float f) {   // fp32 -> bf16 RNE
    unsigned int u = __float_as_uint(f);
    u += 0x7fffu + ((u >> 16) & 1u);
    return (unsigned short)(u >> 16);
}
__device__ __forceinline__ float b2f(unsigned short s) {
    return __uint_as_float(((unsigned int)s) << 16);
}

__device__ __forceinline__ void gload_lds16(const void* gp, void* lp) {
    __builtin_amdgcn_global_load_lds(
        (const __attribute__((address_space(1))) unsigned int*)gp,
        (__attribute__((address_space(3))) unsigned int*)lp, 16, 0, 0);
}

// ================= CSR build (once per call) =================
__global__ __launch_bounds__(256)
void deg_kernel(const int* __restrict__ edges, int* __restrict__ deg) {
    int eg = blockIdx.x * 256 + threadIdx.x;
    if (eg >= TT * EE) return;
    int t = eg / EE;
    int tgt = edges[eg * 2 + 1];
    atomicAdd(&deg[t * NN + tgt], 1);
}

__global__ __launch_bounds__(256)
void scan_block(const int* __restrict__ deg, int* __restrict__ locscan,
                int* __restrict__ blocksum) {
    __shared__ int sh[256];
    const int tid = threadIdx.x;
    const int i = blockIdx.x * 256 + tid;
    int v = (i < TN) ? deg[i] : 0;
    sh[tid] = v;
    __syncthreads();
    #pragma unroll
    for (int off = 1; off < 256; off <<= 1) {
        int t = (tid >= off) ? sh[tid - off] : 0;
        __syncthreads();
        sh[tid] += t;
        __syncthreads();
    }
    if (i < TN) locscan[i] = sh[tid];
    if (tid == 255) blocksum[blockIdx.x] = sh[255];
}

__global__ __launch_bounds__(1024)
void scan_partials(const int* __restrict__ blocksum, int* __restrict__ blockpref) {
    __shared__ int sh[1024];
    const int tid = threadIdx.x;
    sh[tid] = (tid < NBLK) ? blocksum[tid] : 0;
    __syncthreads();
    #pragma unroll
    for (int off = 1; off < 1024; off <<= 1) {
        int t = (tid >= off) ? sh[tid - off] : 0;
        __syncthreads();
        sh[tid] += t;
        __syncthreads();
    }
    if (tid < NBLK) blockpref[tid] = (tid == 0) ? 0 : sh[tid - 1];
}

__global__ __launch_bounds__(256)
void fill_base(const int* __restrict__ deg, const int* __restrict__ locscan,
               const int* __restrict__ blockpref, int* __restrict__ base,
               int* __restrict__ cursor) {
    const int i = blockIdx.x * 256 + threadIdx.x;
    if (i >= TN) return;
    const int incl = locscan[i] + blockpref[blockIdx.x];
    base[i] = incl - deg[i];
    cursor[i] = 0;
    if (i == TN - 1) base[TN] = incl;
}

__global__ __launch_bounds__(256)
void place_kernel(const int* __restrict__ edges, const int* __restrict__ base,
                  int* __restrict__ cursor, unsigned short* __restrict__ srcs) {
    int eg = blockIdx.x * 256 + threadIdx.x;
    if (eg >= TT * EE) return;
    int t = eg / EE;
    int src = edges[eg * 2];
    int tgt = edges[eg * 2 + 1];
    int idx = t * NN + tgt;
    int p = base[idx] + atomicAdd(&cursor[idx], 1);
    srcs[p] = (unsigned short)src;
}

__global__ __launch_bounds__(256)
void deg_to_f(const int* __restrict__ base, float* __restrict__ degf) {
    int n = blockIdx.x * 256 + threadIdx.x;
    if (n >= NN) return;
    float4 d;
    d.x = (float)(base[n + 1] - base[n]);
    d.y = (float)(base[NN + n + 1] - base[NN + n]);
    d.z = (float)(base[2 * NN + n + 1] - base[2 * NN + n]);
    d.w = (float)(base[3 * NN + n + 1] - base[3 * NN + n]);
    *(float4*)&degf[(size_t)n * 4] = d;
}

// ================= fp32 -> bf16 convert =================
__global__ __launch_bounds__(256)
void convb(const float* __restrict__ src, unsigned short* __restrict__ dst, int n) {
    int i = blockIdx.x * 256 + threadIdx.x;
    if (i < n) dst[i] = f2b(src[i]);
}

// ================= gather: S[row] = sum_bf16 h[src] =================
__global__ __launch_bounds__(256)
void gather_kernel(const int* __restrict__ base, const unsigned short* __restrict__ srcs,
                   const unsigned short* __restrict__ hb, unsigned short* __restrict__ S) {
    int gid = blockIdx.x * 256 + threadIdx.x;
    int row = gid >> 5;
    int c = (gid & 31) * 4;
    const int p0 = base[row];
    const int p1 = base[row + 1];
    float a0 = 0.f, a1 = 0.f, a2 = 0.f, a3 = 0.f;
    for (int p = p0; p < p1; ++p) {
        const ushort4 v = *(const ushort4*)&hb[(size_t)srcs[p] * HH + c];
        a0 += b2f(v.x); a1 += b2f(v.y); a2 += b2f(v.z); a3 += b2f(v.w);
    }
    ushort4 o;
    o.x = f2b(a0); o.y = f2b(a1); o.z = f2b(a2); o.w = f2b(a3);
    *(ushort4*)&S[(size_t)row * HH + c] = o;
}

// ================= bf16 MFMA GEMM =================
// C[M x N=128*gridDim.y] = A @ B^T (+ epilogue), all bf16 in, fp32 acc, bf16 out.
// AMODE 0: A = concat(A0 rows lda=K0, A1 rows lda=K-K0); B row-major (F, K).
// AMODE 1: A = segmented-t: el(row, k) = A0[(k>>7)*segA + row*128 + (k&127)];
//          B el(f, k) = B[(k>>7)*16384 + f*128 + (k&127)]   (msg_W layout).
// EPI 0: + bias[col];  EPI 1: + sum_t degf[row*4+t] * bias[t*128+col].
// 128x128 tile, 4 waves (2x2), each 64x64 via 4x4 mfma_f32_16x16x32_bf16.
// LDS XOR-swizzle (chunk ^= row&7) keeps ds_read_b128 conflict-free while
// satisfying global_load_lds's contiguous lane->LDS mapping.
template<int AMODE, int EPI>
__global__ __launch_bounds__(256)
void mfma_gemm(const unsigned short* __restrict__ A0,
               const unsigned short* __restrict__ A1, int K0, int K, long segA,
               const unsigned short* __restrict__ B,
               const float* __restrict__ bias,
               const float* __restrict__ degf,
               unsigned short* __restrict__ C, int ldc, int M) {
    __shared__ unsigned short lsA[128 * 64];
    __shared__ unsigned short lsB[128 * 64];
    const int tid = threadIdx.x;
    const int lane = tid & 63;
    const int w = tid >> 6;
    const int wm = w >> 1, wn = w & 1;
    const int ln15 = lane & 15;
    const int quad = lane >> 4;
    const int swz = ln15 & 7;
    const int mbase = blockIdx.x * 128;
    const int fbase = blockIdx.y * 128;
    const int qg = (lane & 7) ^ (lane >> 3);   // swizzled chunk slot for staging

    f32x4 acc[4][4];
    #pragma unroll
    for (int i = 0; i < 4; ++i)
        #pragma unroll
        for (int j = 0; j < 4; ++j)
            acc[i][j] = (f32x4){0.f, 0.f, 0.f, 0.f};

    const int ntiles = K >> 6;
    for (int tile = 0; tile < ntiles; ++tile) {
        const int ck0 = tile << 3;
        #pragma unroll
        for (int i = 0; i < 4; ++i) {
            const int r = i * 32 + (w << 3) + (lane >> 3);
            const int chunk = ck0 + qg;
            int grow = mbase + r;
            if (grow > M - 1) grow = M - 1;
            const unsigned short* gpA;
            if (AMODE == 0) {
                const int kel = chunk << 3;
                gpA = (kel < K0) ? (A0 + (size_t)grow * K0 + kel)
                                 : (A1 + (size_t)grow * (K - K0) + (kel - K0));
            } else {
                gpA = A0 + (size_t)(chunk >> 4) * segA + (size_t)grow * 128 + ((chunk & 15) << 3);
            }
            gload_lds16(gpA, &lsA[(i * 32 + (w << 3)) * 64]);
            const unsigned short* gpB;
            if (AMODE == 0) {
                gpB = B + (size_t)(fbase + r) * K + (chunk << 3);
            } else {
                gpB = B + (size_t)(chunk >> 4) * 16384 + (size_t)r * 128 + ((chunk & 15) << 3);
            }
            gload_lds16(gpB, &lsB[(i * 32 + (w << 3)) * 64]);
        }
        __syncthreads();
        #pragma unroll
        for (int kk = 0; kk < 2; ++kk) {
            const int cs = (((kk * 4 + quad) ^ swz)) << 3;
            bfrag8 aF[4], bF[4];
            #pragma unroll
            for (int mt = 0; mt < 4; ++mt)
                aF[mt] = *(const bfrag8*)&lsA[(wm * 64 + mt * 16 + ln15) * 64 + cs];
            #pragma unroll
            for (int nt = 0; nt < 4; ++nt)
                bF[nt] = *(const bfrag8*)&lsB[(wn * 64 + nt * 16 + ln15) * 64 + cs];
            #pragma unroll
            for (int mt = 0; mt < 4; ++mt)
                #pragma unroll
                for (int nt = 0; nt < 4; ++nt)
                    acc[mt][nt] = __builtin_amdgcn_mfma_f32_16x16x32_bf16(
                        aF[mt], bF[nt], acc[mt][nt], 0, 0, 0);
        }
        __syncthreads();
    }

    // epilogue
    float bcol[4];
    float bs[4][4];
    if (EPI == 0) {
        #pragma unroll
        for (int nt = 0; nt < 4; ++nt)
            bcol[nt] = bias[fbase + wn * 64 + nt * 16 + ln15];
    } else {
        #pragma unroll
        for (int nt = 0; nt < 4; ++nt) {
            const int col = wn * 64 + nt * 16 + ln15;
            #pragma unroll
            for (int t = 0; t < 4; ++t) bs[t][nt] = bias[t * 128 + col];
        }
    }
    #pragma unroll
    for (int mt = 0; mt < 4; ++mt) {
        #pragma unroll
        for (int reg = 0; reg < 4; ++reg) {
            const int grow = mbase + wm * 64 + mt * 16 + quad * 4 + reg;
            if (grow < M) {
                float4 dv = make_float4(0.f, 0.f, 0.f, 0.f);
                if (EPI == 1) dv = *(const float4*)&degf[(size_t)grow * 4];
                #pragma unroll
                for (int nt = 0; nt < 4; ++nt) {
                    float v = acc[mt][nt][reg];
                    if (EPI == 0) v += bcol[nt];
                    else v += dv.x * bs[0][nt] + dv.y * bs[1][nt]
                            + dv.z * bs[2][nt] + dv.w * bs[3][nt];
                    const int gcol = fbase + wn * 64 + nt * 16 + ln15;
                    C[(size_t)grow * ldc + gcol] = f2b(v);
                }
            }
        }
    }
}

// ================= GRU gates =================
__global__ __launch_bounds__(256)
void gate_kernel(const unsigned short* __restrict__ gxb, const unsigned short* __restrict__ ghb,
                 const float* __restrict__ hcur, float* __restrict__ hnext,
                 unsigned short* __restrict__ hbn) {
    int gid = blockIdx.x * 256 + threadIdx.x;
    int n = gid >> 5;
    int c = (gid & 31) * 4;
    const size_t bx = (size_t)n * 384 + c;
    const ushort4 uxr = *(const ushort4*)&gxb[bx];
    const ushort4 uxz = *(const ushort4*)&gxb[bx + 128];
    const ushort4 uxn = *(const ushort4*)&gxb[bx + 256];
    const ushort4 uhr = *(const ushort4*)&ghb[bx];
    const ushort4 uhz = *(const ushort4*)&ghb[bx + 128];
    const ushort4 uhn = *(const ushort4*)&ghb[bx + 256];
    const float4 hv = *(const float4*)&hcur[(size_t)n * HH + c];
    float4 o;
    o.x = gru_elem(b2f(uxr.x), b2f(uxz.x), b2f(uxn.x), b2f(uhr.x), b2f(uhz.x), b2f(uhn.x), hv.x);
    o.y = gru_elem(b2f(uxr.y), b2f(uxz.y), b2f(uxn.y), b2f(uhr.y), b2f(uhz.y), b2f(uhn.y), hv.y);
    o.z = gru_elem(b2f(uxr.z), b2f(uxz.z), b2f(uxn.z), b2f(uhr.z), b2f(uhz.z), b2f(uhn.z), hv.z);
    o.w = gru_elem(b2f(uxr.w), b2f(uxz.w), b2f(uxn.w), b2f(uhr.w), b2f(uhz.w), b2f(uhn.w), hv.w);
    *(float4*)&hnext[(size_t)n * HH + c] = o;
    ushort4 ob;
    ob.x = f2b(o.x); ob.y = f2b(o.y); ob.z = f2b(o.z); ob.w = f2b(o.w);
    *(ushort4*)&hbn[(size_t)n * HH + c] = ob;
}

extern "C" void kernel_launch(void* const* d_in, const int* in_sizes, int n_in,
                              void* d_out, int out_size, void* d_ws, size_t ws_size,
                              hipStream_t stream) {
    (void)in_sizes; (void)n_in; (void)out_size; (void)ws_size;
    const float* x     = (const float*)d_in[0];
    const int*   edges = (const int*)d_in[1];
    const float* msg_W = (const float*)d_in[2];
    const float* msg_b = (const float*)d_in[3];
    const float* W0ih  = (const float*)d_in[4];
    const float* W0hh  = (const float*)d_in[5];
    const float* b0ih  = (const float*)d_in[6];
    const float* b0hh  = (const float*)d_in[7];
    const float* W1ih  = (const float*)d_in[8];
    const float* W1hh  = (const float*)d_in[9];
    const float* b1ih  = (const float*)d_in[10];
    const float* b1hh  = (const float*)d_in[11];
    float* out = (float*)d_out;

    // ---- workspace layout (float units) ----
    // region0 [0, 19.2M): Sb (gather->inc_gemm) then gxb+ghb (gemms->gate); disjoint lifetimes.
    float* ws = (float*)d_ws;
    unsigned short* Sb   = (unsigned short*)ws;                  // TN*128 u16 = 12.8M fl
    unsigned short* gxb  = (unsigned short*)ws;                  // N*384 u16 = 9.6M fl
    unsigned short* ghb  = (unsigned short*)(ws + 9600000);      // N*384 u16
    unsigned short* incb = (unsigned short*)(ws + 19200000);     // N*128 u16 = 3.2M fl
    unsigned short* xb   = (unsigned short*)(ws + 22400000);     // N*128 u16
    unsigned short* hb   = (unsigned short*)(ws + 25600000);     // N*128 u16
    float* hA            = ws + 28800000;                        // N*128 fp32
    unsigned short* wb   = (unsigned short*)(ws + 35200000);     // bf16 weights
    unsigned short* msgWb = wb;              // 2*4*128*128 = 131072
    unsigned short* W0ihb = wb + 131072;     // 49152
    unsigned short* W0hhb = wb + 180224;     // 49152
    unsigned short* W1ihb = wb + 229376;     // 98304
    unsigned short* W1hhb = wb + 327680;     // 49152
    float* degf          = ws + 35400000;                        // N*4 fp32
    int*   base          = (int*)(ws + 35600000);                // TN+1 ints
    unsigned short* srcs = (unsigned short*)(ws + 35800004);     // T*E u16
    // build temporaries alias region0 (dead before first gather)
    int* deg_tmp   = (int*)ws;
    int* locscan   = deg_tmp + TN;
    int* cursor    = deg_tmp + 2 * TN;
    int* blocksum  = deg_tmp + 3 * TN;
    int* blockpref = deg_tmp + 3 * TN + 1024;

    hipMemcpyAsync(out, x, (size_t)NN * HH * sizeof(float), hipMemcpyDeviceToDevice, stream);

    // ---- CSR build ----
    hipMemsetAsync(deg_tmp, 0, (size_t)TN * sizeof(int), stream);
    deg_kernel<<<(TT * EE + 255) / 256, 256, 0, stream>>>(edges, deg_tmp);
    scan_block<<<NBLK, 256, 0, stream>>>(deg_tmp, locscan, blocksum);
    scan_partials<<<1, 1024, 0, stream>>>(blocksum, blockpref);
    fill_base<<<NBLK, 256, 0, stream>>>(deg_tmp, locscan, blockpref, base, cursor);
    place_kernel<<<(TT * EE + 255) / 256, 256, 0, stream>>>(edges, base, cursor, srcs);
    deg_to_f<<<(NN + 255) / 256, 256, 0, stream>>>(base, degf);

    // ---- bf16 conversions (once per call) ----
    convb<<<(2 * TT * HH * HH + 255) / 256, 256, 0, stream>>>(msg_W, msgWb, 2 * TT * HH * HH);
    convb<<<(384 * 128 + 255) / 256, 256, 0, stream>>>(W0ih, W0ihb, 384 * 128);
    convb<<<(384 * 128 + 255) / 256, 256, 0, stream>>>(W0hh, W0hhb, 384 * 128);
    convb<<<(384 * 256 + 255) / 256, 256, 0, stream>>>(W1ih, W1ihb, 384 * 256);
    convb<<<(384 * 128 + 255) / 256, 256, 0, stream>>>(W1hh, W1hhb, 384 * 128);
    convb<<<(NN * HH + 255) / 256, 256, 0, stream>>>(x, xb, NN * HH);
    convb<<<(NN * HH + 255) / 256, 256, 0, stream>>>(x, hb, NN * HH);   // h0 = x

    const int mblocks = (NN + 127) / 128;  // 391
    for (int s = 0; s < 6; ++s) {
        const int l = s / 3;
        const float* hcur  = (s % 2 == 0) ? out : hA;
        float*       hnext = (s % 2 == 0) ? hA : out;

        gather_kernel<<<(TN * 32) / 256, 256, 0, stream>>>(base, srcs, hb, Sb);
        mfma_gemm<1, 1><<<dim3(mblocks, 1), 256, 0, stream>>>(
            Sb, Sb, 512, 512, (long)NN * 128, msgWb + (size_t)l * 65536,
            msg_b + (size_t)l * 512, degf, incb, 128, NN);
        if (l == 0) {
            mfma_gemm<0, 0><<<dim3(mblocks, 3), 256, 0, stream>>>(
                incb, incb, 128, 128, 0, W0ihb, b0ih, nullptr, gxb, 384, NN);
            mfma_gemm<0, 0><<<dim3(mblocks, 3), 256, 0, stream>>>(
                hb, hb, 128, 128, 0, W0hhb, b0hh, nullptr, ghb, 384, NN);
        } else {
            mfma_gemm<0, 0><<<dim3(mblocks, 3), 256, 0, stream>>>(
                xb, incb, 128, 256, 0, W1ihb, b1ih, nullptr, gxb, 384, NN);
            mfma_gemm<0, 0><<<dim3(mblocks, 3), 256, 0, stream>>>(
                hb, hb, 128, 128, 0, W1hhb, b1hh, nullptr, ghb, 384, NN);
        }
        gate_kernel<<<(NN * 32) / 256, 256, 0, stream>>>(gxb, ghb, hcur, hnext, hb);
    }
}

// Round 4
// 816.264 us; speedup vs baseline: 10.0526x; 1.2156x over previous
//
#include <hip/hip_runtime.h>
#include <cstddef>

#define NN 50000
#define HH 128
#define TT 4
#define EE 150000

typedef __attribute__((ext_vector_type(8))) short bfrag8;   // 8 bf16 = 4 VGPRs
typedef __attribute__((ext_vector_type(4))) float f32x4;
typedef __attribute__((ext_vector_type(8))) unsigned short u16x8;

__device__ __forceinline__ float sigm(float v) { return 1.0f / (1.0f + __expf(-v)); }

__device__ __forceinline__ float gru_elem(float xr, float xz, float xn,
                                          float hr, float hz, float hn, float h) {
    float r = sigm(xr + hr);
    float z = sigm(xz + hz);
    float nn = tanhf(xn + r * hn);
    return (1.f - z) * nn + z * h;
}

__device__ __forceinline__ unsigned short f2b(float f) {   // fp32 -> bf16 RNE
    unsigned int u = __float_as_uint(f);
    u += 0x7fffu + ((u >> 16) & 1u);
    return (unsigned short)(u >> 16);
}
__device__ __forceinline__ float b2f(unsigned short s) {
    return __uint_as_float(((unsigned int)s) << 16);
}

__device__ __forceinline__ void gload_lds16(const void* gp, void* lp) {
    __builtin_amdgcn_global_load_lds(
        (const __attribute__((address_space(1))) unsigned int*)gp,
        (__attribute__((address_space(3))) unsigned int*)lp, 16, 0, 0);
}

// ================= CSR build over target node n (once per call) =================
__global__ __launch_bounds__(256)
void deg2_kernel(const int* __restrict__ edges, int* __restrict__ deg) {
    int eg = blockIdx.x * 256 + threadIdx.x;
    if (eg >= TT * EE) return;
    int tgt = edges[eg * 2 + 1];
    atomicAdd(&deg[tgt], 1);
}

__global__ __launch_bounds__(256)
void scan_block(const int* __restrict__ d, int* __restrict__ loc,
                int* __restrict__ bsum, int n) {
    __shared__ int sh[256];
    const int tid = threadIdx.x;
    const int i = blockIdx.x * 256 + tid;
    int v = (i < n) ? d[i] : 0;
    sh[tid] = v;
    __syncthreads();
    #pragma unroll
    for (int off = 1; off < 256; off <<= 1) {
        int t = (tid >= off) ? sh[tid - off] : 0;
        __syncthreads();
        sh[tid] += t;
        __syncthreads();
    }
    if (i < n) loc[i] = sh[tid];
    if (tid == 255) bsum[blockIdx.x] = sh[255];
}

__global__ __launch_bounds__(1024)
void scan_partials(const int* __restrict__ bsum, int* __restrict__ bpref, int nblk) {
    __shared__ int sh[1024];
    const int tid = threadIdx.x;
    sh[tid] = (tid < nblk) ? bsum[tid] : 0;
    __syncthreads();
    #pragma unroll
    for (int off = 1; off < 1024; off <<= 1) {
        int t = (tid >= off) ? sh[tid - off] : 0;
        __syncthreads();
        sh[tid] += t;
        __syncthreads();
    }
    if (tid < nblk) bpref[tid] = (tid == 0) ? 0 : sh[tid - 1];
}

__global__ __launch_bounds__(256)
void fill_base(const int* __restrict__ d, const int* __restrict__ loc,
               const int* __restrict__ bpref, int* __restrict__ base,
               int* __restrict__ cursor, int n) {
    const int i = blockIdx.x * 256 + threadIdx.x;
    if (i >= n) return;
    const int incl = loc[i] + bpref[blockIdx.x];
    base[i] = incl - d[i];
    cursor[i] = 0;
    if (i == n - 1) base[n] = incl;
}

// payload: element offset of the gathered 128-col slice in Z: src*512 + t*128
__global__ __launch_bounds__(256)
void place2_kernel(const int* __restrict__ edges, const int* __restrict__ base,
                   int* __restrict__ cursor, unsigned int* __restrict__ rows) {
    int eg = blockIdx.x * 256 + threadIdx.x;
    if (eg >= TT * EE) return;
    int t = eg / EE;
    int src = edges[eg * 2];
    int tgt = edges[eg * 2 + 1];
    int p = base[tgt] + atomicAdd(&cursor[tgt], 1);
    rows[p] = (unsigned int)src * 512u + (unsigned int)t * 128u;
}

// ================= fp32 -> bf16 convert =================
__global__ __launch_bounds__(256)
void convb(const float* __restrict__ src, unsigned short* __restrict__ dst, int n) {
    int i = blockIdx.x * 256 + threadIdx.x;
    if (i < n) dst[i] = f2b(src[i]);
}

// permuted weight convert: row f of (384,K) -> row' = ((f&127)>>4)*48 + (f>>7)*16 + (f&15)
__global__ __launch_bounds__(256)
void permW(const float* __restrict__ src, unsigned short* __restrict__ dst, int K) {
    int i = blockIdx.x * 256 + threadIdx.x;
    if (i >= 384 * K) return;
    int f = i / K, k = i - f * K;
    int gc = f & 127, ch = f >> 7;
    int rp = (gc >> 4) * 48 + ch * 16 + (gc & 15);
    dst[rp * K + k] = f2b(src[i]);
}

__global__ __launch_bounds__(256)
void permBias(const float* __restrict__ src, float* __restrict__ dst) {
    int f = blockIdx.x * 256 + threadIdx.x;
    if (f >= 384) return;
    int gc = f & 127, ch = f >> 7;
    int rp = (gc >> 4) * 48 + ch * 16 + (gc & 15);
    dst[rp] = src[f];
}

// ================= gather: inc[n] = sum_edges Z[rows[p] + c] =================
// 16 lanes (u16x8 each) per node row; grid exact: NN*16/256
__global__ __launch_bounds__(256)
void gather2(const int* __restrict__ base, const unsigned int* __restrict__ rows,
             const unsigned short* __restrict__ Z, unsigned short* __restrict__ incb) {
    int gid = blockIdx.x * 256 + threadIdx.x;
    int n = gid >> 4;
    int c = (gid & 15) * 8;
    const int p0 = base[n];
    const int p1 = base[n + 1];
    float a[8] = {};
    int p = p0;
    for (; p + 4 <= p1; p += 4) {
        unsigned int o0 = rows[p], o1 = rows[p + 1], o2 = rows[p + 2], o3 = rows[p + 3];
        u16x8 v0 = *(const u16x8*)&Z[o0 + c];
        u16x8 v1 = *(const u16x8*)&Z[o1 + c];
        u16x8 v2 = *(const u16x8*)&Z[o2 + c];
        u16x8 v3 = *(const u16x8*)&Z[o3 + c];
        #pragma unroll
        for (int j = 0; j < 8; ++j)
            a[j] += (b2f((unsigned short)v0[j]) + b2f((unsigned short)v1[j]))
                  + (b2f((unsigned short)v2[j]) + b2f((unsigned short)v3[j]));
    }
    for (; p < p1; ++p) {
        u16x8 v = *(const u16x8*)&Z[rows[p] + c];
        #pragma unroll
        for (int j = 0; j < 8; ++j) a[j] += b2f((unsigned short)v[j]);
    }
    u16x8 o;
    #pragma unroll
    for (int j = 0; j < 8; ++j) o[j] = f2b(a[j]);
    *(u16x8*)&incb[(size_t)n * 128 + c] = o;
}

// ================= bf16 MFMA GEMM: C = [A0|A1] @ B^T + bias =================
// 128x128 tile, 4 waves (2x2), each 64x64 via 4x4 mfma_f32_16x16x32_bf16.
__global__ __launch_bounds__(256)
void mfma_gemm(const unsigned short* __restrict__ A0,
               const unsigned short* __restrict__ A1, int K0, int K,
               const unsigned short* __restrict__ B,
               const float* __restrict__ bias,
               unsigned short* __restrict__ C, int ldc, int M) {
    __shared__ unsigned short lsA[128 * 64];
    __shared__ unsigned short lsB[128 * 64];
    const int tid = threadIdx.x;
    const int lane = tid & 63;
    const int w = tid >> 6;
    const int wm = w >> 1, wn = w & 1;
    const int ln15 = lane & 15;
    const int quad = lane >> 4;
    const int swz = ln15 & 7;
    const int mbase = blockIdx.x * 128;
    const int fbase = blockIdx.y * 128;
    const int qg = (lane & 7) ^ (lane >> 3);

    f32x4 acc[4][4];
    #pragma unroll
    for (int i = 0; i < 4; ++i)
        #pragma unroll
        for (int j = 0; j < 4; ++j)
            acc[i][j] = (f32x4){0.f, 0.f, 0.f, 0.f};

    const int ntiles = K >> 6;
    for (int tile = 0; tile < ntiles; ++tile) {
        const int ck0 = tile << 3;
        #pragma unroll
        for (int i = 0; i < 4; ++i) {
            const int r = i * 32 + (w << 3) + (lane >> 3);
            const int chunk = ck0 + qg;
            int grow = mbase + r;
            if (grow > M - 1) grow = M - 1;
            const int kel = chunk << 3;
            const unsigned short* gpA =
                (kel < K0) ? (A0 + (size_t)grow * K0 + kel)
                           : (A1 + (size_t)grow * (K - K0) + (kel - K0));
            gload_lds16(gpA, &lsA[(i * 32 + (w << 3)) * 64]);
            const unsigned short* gpB = B + (size_t)(fbase + r) * K + kel;
            gload_lds16(gpB, &lsB[(i * 32 + (w << 3)) * 64]);
        }
        __syncthreads();
        #pragma unroll
        for (int kk = 0; kk < 2; ++kk) {
            const int cs = (((kk * 4 + quad) ^ swz)) << 3;
            bfrag8 aF[4], bF[4];
            #pragma unroll
            for (int mt = 0; mt < 4; ++mt)
                aF[mt] = *(const bfrag8*)&lsA[(wm * 64 + mt * 16 + ln15) * 64 + cs];
            #pragma unroll
            for (int nt = 0; nt < 4; ++nt)
                bF[nt] = *(const bfrag8*)&lsB[(wn * 64 + nt * 16 + ln15) * 64 + cs];
            #pragma unroll
            for (int mt = 0; mt < 4; ++mt)
                #pragma unroll
                for (int nt = 0; nt < 4; ++nt)
                    acc[mt][nt] = __builtin_amdgcn_mfma_f32_16x16x32_bf16(
                        aF[mt], bF[nt], acc[mt][nt], 0, 0, 0);
        }
        __syncthreads();
    }

    float bcol[4];
    #pragma unroll
    for (int nt = 0; nt < 4; ++nt)
        bcol[nt] = bias[fbase + wn * 64 + nt * 16 + ln15];
    #pragma unroll
    for (int mt = 0; mt < 4; ++mt) {
        #pragma unroll
        for (int reg = 0; reg < 4; ++reg) {
            const int grow = mbase + wm * 64 + mt * 16 + quad * 4 + reg;
            if (grow < M) {
                #pragma unroll
                for (int nt = 0; nt < 4; ++nt) {
                    const int gcol = fbase + wn * 64 + nt * 16 + ln15;
                    C[(size_t)grow * ldc + gcol] = f2b(acc[mt][nt][reg] + bcol[nt]);
                }
            }
        }
    }
}

// ================= fused gh-GEMM + GRU gate =================
// gh = hb @ WhhP^T (K=128, F=384 permuted r/z/n-by-16); epilogue applies gates.
// 512 threads, M-tile 64, 8 waves each 64 rows x 48 cols (nt = r,z,n chunk).
__global__ __launch_bounds__(512)
void ghgate_kernel(const unsigned short* __restrict__ hb,
                   const unsigned short* __restrict__ Wp,
                   const float* __restrict__ bp,
                   const unsigned short* __restrict__ gx,
                   const float* __restrict__ hcur,
                   float* __restrict__ hnext, unsigned short* __restrict__ hbn,
                   int M) {
    __shared__ unsigned short lsA[64 * 64];    // 8 KB
    __shared__ unsigned short lsB[384 * 64];   // 48 KB
    const int tid = threadIdx.x;
    const int lane = tid & 63;
    const int w = tid >> 6;             // 0..7
    const int ln15 = lane & 15;
    const int quad = lane >> 4;
    const int swz = ln15 & 7;
    const int mbase = blockIdx.x * 64;
    const int srow = tid >> 3;          // staging row 0..63
    const int slot = tid & 7;

    f32x4 acc[4][3];
    #pragma unroll
    for (int i = 0; i < 4; ++i)
        #pragma unroll
        for (int j = 0; j < 3; ++j)
            acc[i][j] = (f32x4){0.f, 0.f, 0.f, 0.f};

    #pragma unroll
    for (int tile = 0; tile < 2; ++tile) {
        const int ck0 = tile << 3;
        // stage A: 64x64 panel, 512 slots == 512 threads
        {
            int grow = mbase + srow;
            if (grow > M - 1) grow = M - 1;
            const int chunk = ck0 + (slot ^ (srow & 7));
            gload_lds16(hb + (size_t)grow * 128 + (chunk << 3), &lsA[tid * 8]);
        }
        // stage B: 6 panels of 64x64
        #pragma unroll
        for (int pi = 0; pi < 6; ++pi) {
            const int brow = pi * 64 + srow;
            const int chunk = ck0 + (slot ^ (srow & 7));
            gload_lds16(Wp + (size_t)brow * 128 + (chunk << 3),
                        &lsB[(pi * 512 + tid) * 8]);
        }
        __syncthreads();
        #pragma unroll
        for (int kk = 0; kk < 2; ++kk) {
            const int cs = ((kk * 4 + quad) ^ swz) << 3;
            bfrag8 aF[4], bF[3];
            #pragma unroll
            for (int mt = 0; mt < 4; ++mt)
                aF[mt] = *(const bfrag8*)&lsA[(mt * 16 + ln15) * 64 + cs];
            #pragma unroll
            for (int nt = 0; nt < 3; ++nt) {
                const int rb = w * 48 + nt * 16 + ln15;
                bF[nt] = *(const bfrag8*)&lsB[rb * 64 + cs];
            }
            #pragma unroll
            for (int mt = 0; mt < 4; ++mt)
                #pragma unroll
                for (int nt = 0; nt < 3; ++nt)
                    acc[mt][nt] = __builtin_amdgcn_mfma_f32_16x16x32_bf16(
                        aF[mt], bF[nt], acc[mt][nt], 0, 0, 0);
        }
        __syncthreads();
    }

    // epilogue: gates
    const float br = bp[w * 48 + ln15];
    const float bz = bp[w * 48 + 16 + ln15];
    const float bn = bp[w * 48 + 32 + ln15];
    const int gc = w * 16 + ln15;
    #pragma unroll
    for (int mt = 0; mt < 4; ++mt) {
        #pragma unroll
        for (int reg = 0; reg < 4; ++reg) {
            const int row = mbase + mt * 16 + quad * 4 + reg;
            if (row < M) {
                const size_t gb = (size_t)row * 384 + w * 48;
                const float xr = b2f(gx[gb + ln15]);
                const float xz = b2f(gx[gb + 16 + ln15]);
                const float xn = b2f(gx[gb + 32 + ln15]);
                const float hrv = acc[mt][0][reg] + br;
                const float hzv = acc[mt][1][reg] + bz;
                const float hnv = acc[mt][2][reg] + bn;
                const float h = hcur[(size_t)row * 128 + gc];
                const float o = gru_elem(xr, xz, xn, hrv, hzv, hnv, h);
                hnext[(size_t)row * 128 + gc] = o;
                hbn[(size_t)row * 128 + gc] = f2b(o);
            }
        }
    }
}

extern "C" void kernel_launch(void* const* d_in, const int* in_sizes, int n_in,
                              void* d_out, int out_size, void* d_ws, size_t ws_size,
                              hipStream_t stream) {
    (void)in_sizes; (void)n_in; (void)out_size; (void)ws_size;
    const float* x     = (const float*)d_in[0];
    const int*   edges = (const int*)d_in[1];
    const float* msg_W = (const float*)d_in[2];
    const float* msg_b = (const float*)d_in[3];
    const float* W0ih  = (const float*)d_in[4];
    const float* W0hh  = (const float*)d_in[5];
    const float* b0ih  = (const float*)d_in[6];
    const float* b0hh  = (const float*)d_in[7];
    const float* W1ih  = (const float*)d_in[8];
    const float* W1hh  = (const float*)d_in[9];
    const float* b1ih  = (const float*)d_in[10];
    const float* b1hh  = (const float*)d_in[11];
    float* out = (float*)d_out;

    // ---- workspace layout (float units) ----
    float* ws = (float*)d_ws;
    unsigned short* Zb   = (unsigned short*)ws;                  // N*512 u16 = 12.8M fl
    unsigned short* gxb  = (unsigned short*)(ws + 12800000);     // N*384 u16 =  9.6M fl
    unsigned short* incb = (unsigned short*)(ws + 22400000);     // N*128 u16 =  3.2M fl
    unsigned short* xb   = (unsigned short*)(ws + 25600000);     // N*128
    unsigned short* hbA  = (unsigned short*)(ws + 28800000);     // N*128
    unsigned short* hbB  = (unsigned short*)(ws + 32000000);     // N*128
    float* hA            = ws + 35200000;                        // N*128 fp32
    unsigned short* wb   = (unsigned short*)(ws + 41600000);
    unsigned short* msgWb = wb;               // 2*4*128*128 = 131072
    unsigned short* W0ihP = wb + 131072;      // 384*128 = 49152
    unsigned short* W0hhP = wb + 180224;      // 49152
    unsigned short* W1ihP = wb + 229376;      // 384*256 = 98304
    unsigned short* W1hhP = wb + 327680;      // 49152
    float* biasP         = ws + 41800000;     // 4 * 384 fp32 (b0ihP,b0hhP,b1ihP,b1hhP)
    float* b0ihP = biasP, *b0hhP = biasP + 384, *b1ihP = biasP + 768, *b1hhP = biasP + 1152;
    int*          base2 = (int*)(ws + 41900000);                 // NN+1
    unsigned int* rows  = (unsigned int*)(ws + 42000000);        // T*E u32
    // build temporaries alias Zb region (dead before step loop)
    int* deg2     = (int*)ws;
    int* locscan  = deg2 + NN;
    int* cursor   = deg2 + 2 * NN;
    int* blocksum = deg2 + 3 * NN;
    int* blockpref= deg2 + 3 * NN + 1024;

    hipMemcpyAsync(out, x, (size_t)NN * HH * sizeof(float), hipMemcpyDeviceToDevice, stream);

    // ---- CSR build (by target node) ----
    const int nblk2 = (NN + 255) / 256;  // 196
    hipMemsetAsync(deg2, 0, (size_t)NN * sizeof(int), stream);
    deg2_kernel<<<(TT * EE + 255) / 256, 256, 0, stream>>>(edges, deg2);
    scan_block<<<nblk2, 256, 0, stream>>>(deg2, locscan, blocksum, NN);
    scan_partials<<<1, 1024, 0, stream>>>(blocksum, blockpref, nblk2);
    fill_base<<<nblk2, 256, 0, stream>>>(deg2, locscan, blockpref, base2, cursor, NN);
    place2_kernel<<<(TT * EE + 255) / 256, 256, 0, stream>>>(edges, base2, cursor, rows);

    // ---- weight conversion / permutation (once per call) ----
    convb<<<(2 * TT * HH * HH + 255) / 256, 256, 0, stream>>>(msg_W, msgWb, 2 * TT * HH * HH);
    permW<<<(384 * 128 + 255) / 256, 256, 0, stream>>>(W0ih, W0ihP, 128);
    permW<<<(384 * 128 + 255) / 256, 256, 0, stream>>>(W0hh, W0hhP, 128);
    permW<<<(384 * 256 + 255) / 256, 256, 0, stream>>>(W1ih, W1ihP, 256);
    permW<<<(384 * 128 + 255) / 256, 256, 0, stream>>>(W1hh, W1hhP, 128);
    permBias<<<2, 256, 0, stream>>>(b0ih, b0ihP);
    permBias<<<2, 256, 0, stream>>>(b0hh, b0hhP);
    permBias<<<2, 256, 0, stream>>>(b1ih, b1ihP);
    permBias<<<2, 256, 0, stream>>>(b1hh, b1hhP);
    convb<<<(NN * HH + 255) / 256, 256, 0, stream>>>(x, xb, NN * HH);
    convb<<<(NN * HH + 255) / 256, 256, 0, stream>>>(x, hbA, NN * HH);   // h0 = x

    const int mblocks = (NN + 127) / 128;   // 391
    const int gblocks = (NN + 63) / 64;     // 782
    for (int s = 0; s < 6; ++s) {
        const int l = s / 3;
        const float* hcur  = (s % 2 == 0) ? out : hA;
        float*       hnext = (s % 2 == 0) ? hA : out;
        unsigned short* hbc = (s % 2 == 0) ? hbA : hbB;
        unsigned short* hbn = (s % 2 == 0) ? hbB : hbA;

        // Z = h @ msgW^T + msg_b  (per-edge bias folded exactly)
        mfma_gemm<<<dim3(mblocks, 4), 256, 0, stream>>>(
            hbc, hbc, 128, 128, msgWb + (size_t)l * 65536,
            msg_b + (size_t)l * 512, Zb, 512, NN);
        gather2<<<(NN * 16) / 256, 256, 0, stream>>>(base2, rows, Zb, incb);
        if (l == 0) {
            mfma_gemm<<<dim3(mblocks, 3), 256, 0, stream>>>(
                incb, incb, 128, 128, W0ihP, b0ihP, gxb, 384, NN);
            ghgate_kernel<<<gblocks, 512, 0, stream>>>(
                hbc, W0hhP, b0hhP, gxb, hcur, hnext, hbn, NN);
        } else {
            mfma_gemm<<<dim3(mblocks, 3), 256, 0, stream>>>(
                xb, incb, 128, 256, W1ihP, b1ihP, gxb, 384, NN);
            ghgate_kernel<<<gblocks, 512, 0, stream>>>(
                hbc, W1hhP, b1hhP, gxb, hcur, hnext, hbn, NN);
        }
    }
    // s=5 writes out (odd parity) — final h lands in d_out.
}